// Round 1
// baseline (748.774 us; speedup 1.0000x reference)
//
#include <hip/hip_runtime.h>

#define NN 40000
#define NE 640000
// D = 128; f32 inputs, indices sniffed i32/i64 at runtime

typedef unsigned short u16;
typedef unsigned int u32;
typedef __attribute__((ext_vector_type(4))) float f32x4;
typedef __attribute__((ext_vector_type(8))) __bf16 bf16x8;

#define LSTR 132  // LDS row stride in elements
#define TPW 8     // tiles (16 edges) per wave in edge_gemm
#define NPW 4

__device__ __forceinline__ float bf2f(u16 u) { return __uint_as_float(((u32)u) << 16); }
__device__ __forceinline__ u16 f2bf(float f) {
  u32 u = __float_as_uint(f);
  u32 r = 0x7fffu + ((u >> 16) & 1u);
  return (u16)((u + r) >> 16);
}
__device__ __forceinline__ float splus(float v) {
  return fmaxf(v, 0.0f) + __logf(1.0f + __expf(-fabsf(v)));
}

// ---------- sniff index dtype ----------
__global__ void sniff_k(const u32* __restrict__ gamma, const u32* __restrict__ eidx,
                        u32* __restrict__ flags) {
  if (threadIdx.x == 0) {
    flags[0] = (gamma[0] == 0x3F803F80u) ? 1u : 0u;
    u32 odd = eidx[1] | eidx[3] | eidx[5] | eidx[7] |
              eidx[9] | eidx[11] | eidx[13] | eidx[15];
    flags[1] = (odd == 0u) ? 1u : 0u;  // int64 indices?
  }
}

__device__ __forceinline__ int load_col(const void* eidx, int e, u32 i64) {
  int nc = i64 ? (int)((const u32*)eidx)[2 * ((size_t)NE + e)]
               : ((const int*)eidx)[NE + e];
  return min(max(nc, 0), NN - 1);
}
__device__ __forceinline__ int load_row(const void* eidx, int e, u32 i64) {
  int nr = i64 ? (int)((const u32*)eidx)[2 * (size_t)e]
               : ((const int*)eidx)[e];
  return min(max(nr, 0), NN - 1);
}

// ---------- weights f32 -> bf16 (sg, dg, du, su, eg) ----------
__global__ __launch_bounds__(256) void wconv5_k(
    const float* __restrict__ W0, const float* __restrict__ W1,
    const float* __restrict__ W2, const float* __restrict__ W3,
    const float* __restrict__ W4, u16* __restrict__ out) {
  int i = blockIdx.x * 256 + threadIdx.x;
  int mtx = blockIdx.y;
  const float* W = (mtx == 0) ? W0 : (mtx == 1) ? W1 : (mtx == 2) ? W2
                 : (mtx == 3) ? W3 : W4;
  out[mtx * 16384 + i] = f2bf(W[i]);
}

// ---------- MFMA helpers ----------
__device__ __forceinline__ bf16x8 a_frag(const float* __restrict__ row, int kbase) {
  float4 f0 = *(const float4*)(row + kbase);
  float4 f1 = *(const float4*)(row + kbase + 4);
  bf16x8 a;
  a[0] = (__bf16)f0.x; a[1] = (__bf16)f0.y; a[2] = (__bf16)f0.z; a[3] = (__bf16)f0.w;
  a[4] = (__bf16)f1.x; a[5] = (__bf16)f1.y; a[6] = (__bf16)f1.z; a[7] = (__bf16)f1.w;
  return a;
}

__device__ __forceinline__ bf16x8 cvt8(float4 a, float4 b) {
  bf16x8 r;
  r[0] = (__bf16)a.x; r[1] = (__bf16)a.y; r[2] = (__bf16)a.z; r[3] = (__bf16)a.w;
  r[4] = (__bf16)b.x; r[5] = (__bf16)b.y; r[6] = (__bf16)b.z; r[7] = (__bf16)b.w;
  return r;
}

__device__ __forceinline__ void gemm16(const bf16x8 af[4], const u16* __restrict__ Wb,
                                       const float* __restrict__ bias, int lane,
                                       f32x4 acc[8]) {
  int l15 = lane & 15, lk = lane >> 4;
#pragma unroll
  for (int n = 0; n < 8; ++n) {
    float bv = bias[n * 16 + l15];
    acc[n] = (f32x4){bv, bv, bv, bv};
  }
#pragma unroll
  for (int n = 0; n < 8; ++n) {
    const u16* bp = Wb + (size_t)(n * 16 + l15) * 128 + lk * 8;
#pragma unroll
    for (int k = 0; k < 4; ++k) {
      bf16x8 b = *(const bf16x8*)(bp + 32 * k);
      acc[n] = __builtin_amdgcn_mfma_f32_16x16x32_bf16(af[k], b, acc[n], 0, 0, 0);
    }
  }
}

__device__ __forceinline__ void store_tile(u16* __restrict__ out, int m0, int lane,
                                           const f32x4 acc[8]) {
  int l15 = lane & 15, lk = lane >> 4;
#pragma unroll
  for (int n = 0; n < 8; ++n)
#pragma unroll
    for (int r = 0; r < 4; ++r)
      out[(size_t)(m0 + lk * 4 + r) * 128 + n * 16 + l15] = f2bf(acc[n][r]);
}

// ---------- kernel 1: 4 node GEMMs via MFMA ----------
__global__ __launch_bounds__(256) void node_gemm_k(
    const float* __restrict__ x, const u16* __restrict__ Wb,
    const float* __restrict__ B0, const float* __restrict__ B1,
    const float* __restrict__ B2, const float* __restrict__ B3,
    u16* __restrict__ o0, u16* __restrict__ o1,
    u16* __restrict__ o2, u16* __restrict__ o3) {
  int tid = threadIdx.x, lane = tid & 63, w = tid >> 6;
  int m0 = blockIdx.x * 64 + w * 16;
  int l15 = lane & 15, lk = lane >> 4;
  const float* arow = x + (size_t)(m0 + l15) * 128;
  bf16x8 af[4];
#pragma unroll
  for (int k = 0; k < 4; ++k) af[k] = a_frag(arow, 32 * k + 8 * lk);
  f32x4 acc[8];
  gemm16(af, Wb + 0 * 16384, B0, lane, acc); store_tile(o0, m0, lane, acc);
  gemm16(af, Wb + 1 * 16384, B1, lane, acc); store_tile(o1, m0, lane, acc);
  gemm16(af, Wb + 2 * 16384, B2, lane, acc); store_tile(o2, m0, lane, acc);
  gemm16(af, Wb + 3 * 16384, B3, lane, acc); store_tile(o3, m0, lane, acc);
}

// ---------- kernel 2: fused edge GEMM + gates + sigmoid + sigma-atomics + edge BN stats ----------
// per 16-edge tile: gather gs[row]+gd[col] -> LDS f32 transpose tile; MFMA edge part;
// C-phase: m = acc + gt (f32), sigma atomics into sigsum[col], e1/e2 stats in regs,
// pack bf16 m -> LDS -> wide stores to mge (mge now holds the FULL gate pre-activation).
__global__ __launch_bounds__(256, 2) void edge_gemm_k(
    const float* __restrict__ ea, const u16* __restrict__ Wgb,
    const float* __restrict__ Bg,
    const u16* __restrict__ g_src, const u16* __restrict__ g_dst,
    const void* __restrict__ eidx,
    u16* __restrict__ mge, float* __restrict__ sigsum,
    float* __restrict__ statsg, const u32* __restrict__ flags) {
  __shared__ __align__(16) u16 mt[4][16][LSTR];
  __shared__ __align__(16) float gt[4][16][LSTR];
  __shared__ u32 cl[4][16];
  int tid = threadIdx.x, lane = tid & 63, w = tid >> 6;
  int l15 = lane & 15, lk = lane >> 4;
  u32 i64 = flags[1];

  // persistent B fragments (128 VGPR) + bias
  bf16x8 bf[8][4];
#pragma unroll
  for (int n = 0; n < 8; ++n)
#pragma unroll
    for (int k = 0; k < 4; ++k)
      bf[n][k] = *(const bf16x8*)(Wgb + (size_t)(n * 16 + l15) * 128 + lk * 8 + 32 * k);
  float bias[8];
#pragma unroll
  for (int n = 0; n < 8; ++n) bias[n] = Bg[n * 16 + l15];

  float e1[8] = {0.f, 0.f, 0.f, 0.f, 0.f, 0.f, 0.f, 0.f};
  float e2[8] = {0.f, 0.f, 0.f, 0.f, 0.f, 0.f, 0.f, 0.f};

  int base = (blockIdx.x * 4 + w) * (TPW * 16);
  const float* aptr = ea + (size_t)(base + l15) * 128 + 8 * lk;

  // prologue: load + convert A tile 0
  float4 tmp[8];
#pragma unroll
  for (int k = 0; k < 4; ++k) {
    tmp[2 * k]     = *(const float4*)(aptr + 32 * k);
    tmp[2 * k + 1] = *(const float4*)(aptr + 32 * k + 4);
  }
  bf16x8 af[4];
#pragma unroll
  for (int k = 0; k < 4; ++k) af[k] = cvt8(tmp[2 * k], tmp[2 * k + 1]);

  for (int t = 0; t < TPW; ++t) {
    int e0 = base + t * 16;
    // ---- gather gs[row]+gd[col] for this tile into gt (lane owns edge lane>>2) ----
    int eg = e0 + (lane >> 2);
    int grow = load_row(eidx, eg, i64);
    int gcol = load_col(eidx, eg, i64);
    if ((lane & 3) == 0) cl[w][lane >> 2] = (u32)gcol;
#pragma unroll
    for (int it = 0; it < 4; ++it) {
      int ch = (lane & 3) + 4 * it;
      uint4 gsv = *(const uint4*)(g_src + (size_t)grow * 128 + ch * 8);
      uint4 gdv = *(const uint4*)(g_dst + (size_t)gcol * 128 + ch * 8);
      const u16* sp = (const u16*)&gsv;
      const u16* dp = (const u16*)&gdv;
      float4 lo, hi;
      lo.x = bf2f(sp[0]) + bf2f(dp[0]);
      lo.y = bf2f(sp[1]) + bf2f(dp[1]);
      lo.z = bf2f(sp[2]) + bf2f(dp[2]);
      lo.w = bf2f(sp[3]) + bf2f(dp[3]);
      hi.x = bf2f(sp[4]) + bf2f(dp[4]);
      hi.y = bf2f(sp[5]) + bf2f(dp[5]);
      hi.z = bf2f(sp[6]) + bf2f(dp[6]);
      hi.w = bf2f(sp[7]) + bf2f(dp[7]);
      *(float4*)&gt[w][lane >> 2][ch * 8]     = lo;
      *(float4*)&gt[w][lane >> 2][ch * 8 + 4] = hi;
    }
    // ---- issue A loads for tile t+1 (independent of this tile's compute) ----
    if (t + 1 < TPW) {
      const float* anx = aptr + (size_t)(t + 1) * 16 * 128;
#pragma unroll
      for (int k = 0; k < 4; ++k) {
        tmp[2 * k]     = *(const float4*)(anx + 32 * k);
        tmp[2 * k + 1] = *(const float4*)(anx + 32 * k + 4);
      }
    }
    // ---- MFMA tile t (B in regs: no memory waits here) ----
    f32x4 acc[8];
#pragma unroll
    for (int n = 0; n < 8; ++n)
      acc[n] = (f32x4){bias[n], bias[n], bias[n], bias[n]};
#pragma unroll
    for (int n = 0; n < 8; ++n)
#pragma unroll
      for (int k = 0; k < 4; ++k)
        acc[n] = __builtin_amdgcn_mfma_f32_16x16x32_bf16(af[k], bf[n][k], acc[n], 0, 0, 0);
    // ---- C-phase: full m (f32), sigmoid + sigma atomics, stats, pack to mt ----
    u32 cr[4];
#pragma unroll
    for (int r = 0; r < 4; ++r) cr[r] = cl[w][lk * 4 + r];
#pragma unroll
    for (int n = 0; n < 8; ++n) {
#pragma unroll
      for (int r = 0; r < 4; ++r) {
        float mv = acc[n][r] + gt[w][lk * 4 + r][n * 16 + l15];
        float sg = 1.0f / (1.0f + __expf(-mv));
        atomicAdd(&sigsum[(size_t)cr[r] * 128 + n * 16 + l15], sg);
        e1[n] += mv;
        e2[n] = fmaf(mv, mv, e2[n]);
        mt[w][lk * 4 + r][n * 16 + l15] = f2bf(mv);
      }
    }
    // ---- convert A tile t+1 (waits on its loads; work above covers latency) ----
    if (t + 1 < TPW) {
#pragma unroll
      for (int k = 0; k < 4; ++k) af[k] = cvt8(tmp[2 * k], tmp[2 * k + 1]);
    }
    // ---- wide stores of full m to mge ----
#pragma unroll
    for (int it = 0; it < 4; ++it) {
      int row = lane >> 2, ch = (lane & 3) + 4 * it;
      uint4 v = *(const uint4*)&mt[w][row][ch * 8];
      *(uint4*)(mge + (size_t)(e0 + row) * 128 + ch * 8) = v;
    }
  }
  // ---- edge BN stats flush: reduce over lk (lanes ^16, ^32), one atomic per feat ----
#pragma unroll
  for (int n = 0; n < 8; ++n) {
    float s1 = e1[n], s2 = e2[n];
    s1 += __shfl_xor(s1, 16); s1 += __shfl_xor(s1, 32);
    s2 += __shfl_xor(s2, 16); s2 += __shfl_xor(s2, 32);
    if (lk == 0) {
      atomicAdd(&statsg[n * 16 + l15], s1);
      atomicAdd(&statsg[128 + n * 16 + l15], s2);
    }
  }
}

// ---------- kernel 3: per-node BN stats over z (z recomputed from sigsum/us/ud) ----------
__global__ __launch_bounds__(256) void node_stats_k(
    const float* __restrict__ sigsum, const u32* __restrict__ us32,
    const u32* __restrict__ ud32, float* __restrict__ statsg) {
  __shared__ float red[256];
  int tid = threadIdx.x, lane = tid & 63, wv = tid >> 6;
  for (int i = tid; i < 256; i += 256) red[i] = 0.f;
  __syncthreads();
  float t1a = 0.f, t2a = 0.f, t1b = 0.f, t2b = 0.f;
  int nbase = (blockIdx.x * 4 + wv) * NPW;
#pragma unroll
  for (int q = 0; q < NPW; ++q) {
    int n = nbase + q;
    float2 a2 = *(const float2*)(sigsum + (size_t)n * 128 + 2 * lane);
    u32 us = us32[(size_t)n * 64 + lane];
    u32 ud = ud32[(size_t)n * 64 + lane];
    float z0 = bf2f((u16)us) + bf2f((u16)ud) * a2.x / (a2.x + 1e-6f);
    float z1 = bf2f((u16)(us >> 16)) + bf2f((u16)(ud >> 16)) * a2.y / (a2.y + 1e-6f);
    t1a += z0; t2a = fmaf(z0, z0, t2a);
    t1b += z1; t2b = fmaf(z1, z1, t2b);
  }
  atomicAdd(&red[2 * lane], t1a);       atomicAdd(&red[2 * lane + 1], t1b);
  atomicAdd(&red[128 + 2 * lane], t2a); atomicAdd(&red[128 + 2 * lane + 1], t2b);
  __syncthreads();
  for (int i = tid; i < 256; i += 256) atomicAdd(&statsg[256 + i], red[i]);
}

// ---------- kernel 4: fold BN stats ----------
__global__ void stats_fin_k(const float* __restrict__ es1, const float* __restrict__ es2,
                            const float* __restrict__ ns1, const float* __restrict__ ns2,
                            const float* __restrict__ eg_, const float* __restrict__ eb_,
                            const float* __restrict__ ng_, const float* __restrict__ nb_,
                            float* __restrict__ params) {
  int d = threadIdx.x;  // 128
  float em = es1[d] * (1.0f / NE);
  float ev = fmaxf(es2[d] * (1.0f / NE) - em * em, 0.0f);
  float esc = eg_[d] * rsqrtf(ev + 1e-5f);
  params[d] = esc;
  params[128 + d] = eb_[d] - em * esc;
  float nm = ns1[d] * (1.0f / NN);
  float nv = fmaxf(ns2[d] * (1.0f / NN) - nm * nm, 0.0f);
  float nsc = ng_[d] * rsqrtf(nv + 1e-5f);
  params[256 + d] = nsc;
  params[384 + d] = nb_[d] - nm * nsc;
}

// ---------- kernel 5: x_out = x + softplus(BN(z)), z recomputed on the fly ----------
__global__ __launch_bounds__(256) void node_fin2_k(
    const float* __restrict__ x, const float* __restrict__ sigsum,
    const u16* __restrict__ us, const u16* __restrict__ ud,
    const float* __restrict__ params, float* __restrict__ out) {
  size_t t = (size_t)blockIdx.x * 256 + threadIdx.x;
  size_t base = t * 8;
  int d0 = (int)(base & 127);
  float4 xa = *(const float4*)(x + base);
  float4 xb = *(const float4*)(x + base + 4);
  float xv[8] = {xa.x, xa.y, xa.z, xa.w, xb.x, xb.y, xb.z, xb.w};
  float4 s0 = *(const float4*)(sigsum + base);
  float4 s1 = *(const float4*)(sigsum + base + 4);
  float av[8] = {s0.x, s0.y, s0.z, s0.w, s1.x, s1.y, s1.z, s1.w};
  uint4 usv = *(const uint4*)(us + base);
  uint4 udv = *(const uint4*)(ud + base);
  const u16* up = (const u16*)&usv;
  const u16* dp = (const u16*)&udv;
  float o[8];
#pragma unroll
  for (int j = 0; j < 8; ++j) {
    float a = av[j];
    float z = bf2f(up[j]) + bf2f(dp[j]) * a / (a + 1e-6f);
    float bnv = z * params[256 + d0 + j] + params[384 + d0 + j];
    o[j] = xv[j] + splus(bnv);
  }
  *(float4*)(out + base) = make_float4(o[0], o[1], o[2], o[3]);
  *(float4*)(out + base + 4) = make_float4(o[4], o[5], o[6], o[7]);
}

// ---------- kernel 6: y_out = edge_attr + softplus(BN(mge)) — pure streaming ----------
__global__ __launch_bounds__(256) void edge_fin_k(
    const float* __restrict__ edge_attr, const u16* __restrict__ mge,
    const float* __restrict__ params, float* __restrict__ out) {
  size_t t = (size_t)blockIdx.x * 256 + threadIdx.x;
  size_t base = t * 8;
  int d0 = (int)(base & 127);
  float4 ea = *(const float4*)(edge_attr + base);
  float4 eb = *(const float4*)(edge_attr + base + 4);
  float ev[8] = {ea.x, ea.y, ea.z, ea.w, eb.x, eb.y, eb.z, eb.w};
  uint4 mv_ = *(const uint4*)(mge + base);
  const u16* mp = (const u16*)&mv_;
  float o[8];
#pragma unroll
  for (int j = 0; j < 8; ++j) {
    float m = bf2f(mp[j]);
    float bnv = m * params[d0 + j] + params[128 + d0 + j];
    o[j] = ev[j] + splus(bnv);
  }
  *(float4*)(out + base) = make_float4(o[0], o[1], o[2], o[3]);
  *(float4*)(out + base + 4) = make_float4(o[4], o[5], o[6], o[7]);
}

// ---------- launch ----------
extern "C" void kernel_launch(void* const* d_in, const int* in_sizes, int n_in,
                              void* d_out, int out_size, void* d_ws, size_t ws_size,
                              hipStream_t stream) {
  const float* x        = (const float*)d_in[0];
  const void*  eidx     = d_in[1];
  const float* edge_att = (const float*)d_in[2];
  const float* Wsg = (const float*)d_in[3];  const float* bsg = (const float*)d_in[4];
  const float* Wdg = (const float*)d_in[5];  const float* bdg = (const float*)d_in[6];
  const float* Weg = (const float*)d_in[7];  const float* beg = (const float*)d_in[8];
  const float* Wsu = (const float*)d_in[9];  const float* bsu = (const float*)d_in[10];
  const float* Wdu = (const float*)d_in[11]; const float* bdu = (const float*)d_in[12];
  const float* bng = (const float*)d_in[13]; const float* bnb = (const float*)d_in[14];
  const float* beg_g = (const float*)d_in[15]; const float* beb = (const float*)d_in[16];

  char* ws = (char*)d_ws;
  u16*   g_src  = (u16*)(ws + 0);              // NN*128 bf16
  u16*   g_dst  = (u16*)(ws + 10240000);
  u16*   u_dst  = (u16*)(ws + 20480000);
  u16*   u_src  = (u16*)(ws + 30720000);
  float* sigsum = (float*)(ws + 40960000);     // NN*128 f32 (20,480,000 B)
  float* stats  = (float*)(ws + 61440000);     // es1,es2,ns1,ns2,params (1024 f32)
  u32*   flags  = (u32*)(ws + 61444096);
  u16*   wbuf   = (u16*)(ws + 61448192);       // 5*16384 bf16
  u16*   mge    = (u16*)(ws + 61612032);       // NE*128 bf16 (full gate pre-activation)

  hipMemsetAsync(stats, 0, 4096, stream);
  hipMemsetAsync(sigsum, 0, 20480000, stream);

  sniff_k<<<1, 64, 0, stream>>>((const u32*)bng, (const u32*)eidx, flags);
  wconv5_k<<<dim3(64, 5), 256, 0, stream>>>(Wsg, Wdg, Wdu, Wsu, Weg, wbuf);
  node_gemm_k<<<NN / 64, 256, 0, stream>>>(x, wbuf, bsg, bdg, bdu, bsu,
                                           g_src, g_dst, u_dst, u_src);
  edge_gemm_k<<<NE / (64 * TPW), 256, 0, stream>>>(edge_att, wbuf + 4 * 16384, beg,
                                                   g_src, g_dst, eidx,
                                                   mge, sigsum, stats, flags);
  node_stats_k<<<NN / 16, 256, 0, stream>>>(sigsum, (const u32*)u_src,
                                            (const u32*)u_dst, stats);
  stats_fin_k<<<1, 128, 0, stream>>>(stats, stats + 128, stats + 256, stats + 384,
                                     beg_g, beb, bng, bnb, stats + 512);
  node_fin2_k<<<(NN * 128) / 2048, 256, 0, stream>>>(x, sigsum, u_src, u_dst,
                                                     stats + 512, (float*)d_out);
  edge_fin_k<<<(NE * 128) / 2048, 256, 0, stream>>>(edge_att, mge, stats + 512,
                                                    (float*)d_out + (size_t)NN * 128);
}

// Round 2
// 558.046 us; speedup vs baseline: 1.3418x; 1.3418x over previous
//
#include <hip/hip_runtime.h>

#define NN 40000
#define NE 640000
// D = 128; f32 inputs, indices sniffed i32/i64 at runtime

typedef unsigned short u16;
typedef unsigned int u32;
typedef __attribute__((ext_vector_type(4))) float f32x4;
typedef __attribute__((ext_vector_type(8))) __bf16 bf16x8;

#define LSTR 132  // LDS row stride in elements
#define TPW 8     // tiles (16 edges) per wave in edge_gemm

__device__ __forceinline__ float bf2f(u16 u) { return __uint_as_float(((u32)u) << 16); }
__device__ __forceinline__ u16 f2bf(float f) {
  u32 u = __float_as_uint(f);
  u32 r = 0x7fffu + ((u >> 16) & 1u);
  return (u16)((u + r) >> 16);
}
__device__ __forceinline__ float splus(float v) {
  return fmaxf(v, 0.0f) + __logf(1.0f + __expf(-fabsf(v)));
}

// ---------- sniff index dtype ----------
__global__ void sniff_k(const u32* __restrict__ gamma, const u32* __restrict__ eidx,
                        u32* __restrict__ flags) {
  if (threadIdx.x == 0) {
    flags[0] = (gamma[0] == 0x3F803F80u) ? 1u : 0u;
    u32 odd = eidx[1] | eidx[3] | eidx[5] | eidx[7] |
              eidx[9] | eidx[11] | eidx[13] | eidx[15];
    flags[1] = (odd == 0u) ? 1u : 0u;  // int64 indices?
  }
}

__device__ __forceinline__ int load_col(const void* eidx, int e, u32 i64) {
  int nc = i64 ? (int)((const u32*)eidx)[2 * ((size_t)NE + e)]
               : ((const int*)eidx)[NE + e];
  return min(max(nc, 0), NN - 1);
}
__device__ __forceinline__ int load_row(const void* eidx, int e, u32 i64) {
  int nr = i64 ? (int)((const u32*)eidx)[2 * (size_t)e]
               : ((const int*)eidx)[e];
  return min(max(nr, 0), NN - 1);
}

// ---------- weights f32 -> bf16 (sg, dg, du, su, eg) ----------
__global__ __launch_bounds__(256) void wconv5_k(
    const float* __restrict__ W0, const float* __restrict__ W1,
    const float* __restrict__ W2, const float* __restrict__ W3,
    const float* __restrict__ W4, u16* __restrict__ out) {
  int i = blockIdx.x * 256 + threadIdx.x;
  int mtx = blockIdx.y;
  const float* W = (mtx == 0) ? W0 : (mtx == 1) ? W1 : (mtx == 2) ? W2
                 : (mtx == 3) ? W3 : W4;
  out[mtx * 16384 + i] = f2bf(W[i]);
}

// ---------- in-degree histogram (deg==0 guard for the gate factor) ----------
__global__ __launch_bounds__(256) void hist_k(const void* __restrict__ eidx,
                                              u32* __restrict__ cnt,
                                              const u32* __restrict__ flags) {
  int e = blockIdx.x * 256 + threadIdx.x;
  atomicAdd(&cnt[load_col(eidx, e, flags[1])], 1u);
}

// ---------- MFMA helpers ----------
__device__ __forceinline__ bf16x8 a_frag(const float* __restrict__ row, int kbase) {
  float4 f0 = *(const float4*)(row + kbase);
  float4 f1 = *(const float4*)(row + kbase + 4);
  bf16x8 a;
  a[0] = (__bf16)f0.x; a[1] = (__bf16)f0.y; a[2] = (__bf16)f0.z; a[3] = (__bf16)f0.w;
  a[4] = (__bf16)f1.x; a[5] = (__bf16)f1.y; a[6] = (__bf16)f1.z; a[7] = (__bf16)f1.w;
  return a;
}

__device__ __forceinline__ bf16x8 cvt8(float4 a, float4 b) {
  bf16x8 r;
  r[0] = (__bf16)a.x; r[1] = (__bf16)a.y; r[2] = (__bf16)a.z; r[3] = (__bf16)a.w;
  r[4] = (__bf16)b.x; r[5] = (__bf16)b.y; r[6] = (__bf16)b.z; r[7] = (__bf16)b.w;
  return r;
}

__device__ __forceinline__ void gemm16(const bf16x8 af[4], const u16* __restrict__ Wb,
                                       const float* __restrict__ bias, int lane,
                                       f32x4 acc[8]) {
  int l15 = lane & 15, lk = lane >> 4;
#pragma unroll
  for (int n = 0; n < 8; ++n) {
    float bv = bias[n * 16 + l15];
    acc[n] = (f32x4){bv, bv, bv, bv};
  }
#pragma unroll
  for (int n = 0; n < 8; ++n) {
    const u16* bp = Wb + (size_t)(n * 16 + l15) * 128 + lk * 8;
#pragma unroll
    for (int k = 0; k < 4; ++k) {
      bf16x8 b = *(const bf16x8*)(bp + 32 * k);
      acc[n] = __builtin_amdgcn_mfma_f32_16x16x32_bf16(af[k], b, acc[n], 0, 0, 0);
    }
  }
}

__device__ __forceinline__ void store_tile(u16* __restrict__ out, int m0, int lane,
                                           const f32x4 acc[8]) {
  int l15 = lane & 15, lk = lane >> 4;
#pragma unroll
  for (int n = 0; n < 8; ++n)
#pragma unroll
    for (int r = 0; r < 4; ++r)
      out[(size_t)(m0 + lk * 4 + r) * 128 + n * 16 + l15] = f2bf(acc[n][r]);
}

// ---------- kernel 1: 4 node GEMMs via MFMA + fused node BN stats ----------
// z = us + (deg>0)*ud computed from f32 accumulators; stats to statsg[256..511].
__global__ __launch_bounds__(256) void node_gemm_k(
    const float* __restrict__ x, const u16* __restrict__ Wb,
    const float* __restrict__ B0, const float* __restrict__ B1,
    const float* __restrict__ B2, const float* __restrict__ B3,
    const u32* __restrict__ cnt,
    u16* __restrict__ o0, u16* __restrict__ o1,
    u16* __restrict__ o2, u16* __restrict__ o3,
    float* __restrict__ statsg) {
  __shared__ float red[256];
  int tid = threadIdx.x, lane = tid & 63, w = tid >> 6;
  for (int i = tid; i < 256; i += 256) red[i] = 0.f;
  __syncthreads();
  int m0 = blockIdx.x * 64 + w * 16;
  int l15 = lane & 15, lk = lane >> 4;
  const float* arow = x + (size_t)(m0 + l15) * 128;
  bf16x8 af[4];
#pragma unroll
  for (int k = 0; k < 4; ++k) af[k] = a_frag(arow, 32 * k + 8 * lk);
  f32x4 acc[8], accd[8];
  gemm16(af, Wb + 0 * 16384, B0, lane, acc);  store_tile(o0, m0, lane, acc);
  gemm16(af, Wb + 1 * 16384, B1, lane, acc);  store_tile(o1, m0, lane, acc);
  gemm16(af, Wb + 2 * 16384, B2, lane, accd); store_tile(o2, m0, lane, accd);
  gemm16(af, Wb + 3 * 16384, B3, lane, acc);  store_tile(o3, m0, lane, acc);
  // fused z-stats: rows m0+lk*4+r, feature n*16+l15
  float g[4];
#pragma unroll
  for (int r = 0; r < 4; ++r) g[r] = (cnt[m0 + lk * 4 + r] != 0u) ? 1.0f : 0.0f;
#pragma unroll
  for (int n = 0; n < 8; ++n) {
    float a1 = 0.f, a2 = 0.f;
#pragma unroll
    for (int r = 0; r < 4; ++r) {
      float zv = acc[n][r] + g[r] * accd[n][r];
      a1 += zv;
      a2 = fmaf(zv, zv, a2);
    }
    a1 += __shfl_xor(a1, 16); a1 += __shfl_xor(a1, 32);
    a2 += __shfl_xor(a2, 16); a2 += __shfl_xor(a2, 32);
    if (lk == 0) {
      atomicAdd(&red[n * 16 + l15], a1);
      atomicAdd(&red[128 + n * 16 + l15], a2);
    }
  }
  __syncthreads();
  for (int i = tid; i < 256; i += 256) atomicAdd(&statsg[256 + i], red[i]);
}

// ---------- kernel 2: fused edge GEMM + gate-add + edge BN stats (NO atom        sigma) ----------
// per 16-edge tile: gather gs[row]+gd[col] -> LDS f32 transpose tile; MFMA edge part;
// C-phase: m = acc + gt (f32), e1/e2 stats in regs, pack bf16 m -> LDS -> wide stores.
__global__ __launch_bounds__(256, 2) void edge_gemm_k(
    const float* __restrict__ ea, const u16* __restrict__ Wgb,
    const float* __restrict__ Bg,
    const u16* __restrict__ g_src, const u16* __restrict__ g_dst,
    const void* __restrict__ eidx,
    u16* __restrict__ mge, float* __restrict__ statsg,
    const u32* __restrict__ flags) {
  __shared__ __align__(16) u16 mt[4][16][LSTR];
  __shared__ __align__(16) float gt[4][16][LSTR];
  int tid = threadIdx.x, lane = tid & 63, w = tid >> 6;
  int l15 = lane & 15, lk = lane >> 4;
  u32 i64 = flags[1];

  // persistent B fragments (128 VGPR) + bias
  bf16x8 bf[8][4];
#pragma unroll
  for (int n = 0; n < 8; ++n)
#pragma unroll
    for (int k = 0; k < 4; ++k)
      bf[n][k] = *(const bf16x8*)(Wgb + (size_t)(n * 16 + l15) * 128 + lk * 8 + 32 * k);
  float bias[8];
#pragma unroll
  for (int n = 0; n < 8; ++n) bias[n] = Bg[n * 16 + l15];

  float e1[8] = {0.f, 0.f, 0.f, 0.f, 0.f, 0.f, 0.f, 0.f};
  float e2[8] = {0.f, 0.f, 0.f, 0.f, 0.f, 0.f, 0.f, 0.f};

  int base = (blockIdx.x * 4 + w) * (TPW * 16);
  const float* aptr = ea + (size_t)(base + l15) * 128 + 8 * lk;

  // prologue: load + convert A tile 0
  float4 tmp[8];
#pragma unroll
  for (int k = 0; k < 4; ++k) {
    tmp[2 * k]     = *(const float4*)(aptr + 32 * k);
    tmp[2 * k + 1] = *(const float4*)(aptr + 32 * k + 4);
  }
  bf16x8 af[4];
#pragma unroll
  for (int k = 0; k < 4; ++k) af[k] = cvt8(tmp[2 * k], tmp[2 * k + 1]);

  for (int t = 0; t < TPW; ++t) {
    int e0 = base + t * 16;
    // ---- gather gs[row]+gd[col] for this tile into gt (lane owns edge lane>>2) ----
    int eg = e0 + (lane >> 2);
    int grow = load_row(eidx, eg, i64);
    int gcol = load_col(eidx, eg, i64);
#pragma unroll
    for (int it = 0; it < 4; ++it) {
      int ch = (lane & 3) + 4 * it;
      uint4 gsv = *(const uint4*)(g_src + (size_t)grow * 128 + ch * 8);
      uint4 gdv = *(const uint4*)(g_dst + (size_t)gcol * 128 + ch * 8);
      const u16* sp = (const u16*)&gsv;
      const u16* dp = (const u16*)&gdv;
      float4 lo, hi;
      lo.x = bf2f(sp[0]) + bf2f(dp[0]);
      lo.y = bf2f(sp[1]) + bf2f(dp[1]);
      lo.z = bf2f(sp[2]) + bf2f(dp[2]);
      lo.w = bf2f(sp[3]) + bf2f(dp[3]);
      hi.x = bf2f(sp[4]) + bf2f(dp[4]);
      hi.y = bf2f(sp[5]) + bf2f(dp[5]);
      hi.z = bf2f(sp[6]) + bf2f(dp[6]);
      hi.w = bf2f(sp[7]) + bf2f(dp[7]);
      *(float4*)&gt[w][lane >> 2][ch * 8]     = lo;
      *(float4*)&gt[w][lane >> 2][ch * 8 + 4] = hi;
    }
    // ---- issue A loads for tile t+1 (independent of this tile's compute) ----
    if (t + 1 < TPW) {
      const float* anx = aptr + (size_t)(t + 1) * 16 * 128;
#pragma unroll
      for (int k = 0; k < 4; ++k) {
        tmp[2 * k]     = *(const float4*)(anx + 32 * k);
        tmp[2 * k + 1] = *(const float4*)(anx + 32 * k + 4);
      }
    }
    // ---- MFMA tile t (B in regs: no memory waits here) ----
    f32x4 acc[8];
#pragma unroll
    for (int n = 0; n < 8; ++n)
      acc[n] = (f32x4){bias[n], bias[n], bias[n], bias[n]};
#pragma unroll
    for (int n = 0; n < 8; ++n)
#pragma unroll
      for (int k = 0; k < 4; ++k)
        acc[n] = __builtin_amdgcn_mfma_f32_16x16x32_bf16(af[k], bf[n][k], acc[n], 0, 0, 0);
    // ---- C-phase: full m (f32), stats, pack to mt ----
#pragma unroll
    for (int n = 0; n < 8; ++n) {
#pragma unroll
      for (int r = 0; r < 4; ++r) {
        float mv = acc[n][r] + gt[w][lk * 4 + r][n * 16 + l15];
        e1[n] += mv;
        e2[n] = fmaf(mv, mv, e2[n]);
        mt[w][lk * 4 + r][n * 16 + l15] = f2bf(mv);
      }
    }
    // ---- convert A tile t+1 (waits on its loads; work above covers latency) ----
    if (t + 1 < TPW) {
#pragma unroll
      for (int k = 0; k < 4; ++k) af[k] = cvt8(tmp[2 * k], tmp[2 * k + 1]);
    }
    // ---- wide stores of full m to mge ----
#pragma unroll
    for (int it = 0; it < 4; ++it) {
      int row = lane >> 2, ch = (lane & 3) + 4 * it;
      uint4 v = *(const uint4*)&mt[w][row][ch * 8];
      *(uint4*)(mge + (size_t)(e0 + row) * 128 + ch * 8) = v;
    }
  }
  // ---- edge BN stats flush: reduce over lk (lanes ^16, ^32), one atomic per feat ----
#pragma unroll
  for (int n = 0; n < 8; ++n) {
    float s1 = e1[n], s2 = e2[n];
    s1 += __shfl_xor(s1, 16); s1 += __shfl_xor(s1, 32);
    s2 += __shfl_xor(s2, 16); s2 += __shfl_xor(s2, 32);
    if (lk == 0) {
      atomicAdd(&statsg[n * 16 + l15], s1);
      atomicAdd(&statsg[128 + n * 16 + l15], s2);
    }
  }
}

// ---------- kernel 3: fold BN stats ----------
__global__ void stats_fin_k(const float* __restrict__ es1, const float* __restrict__ es2,
                            const float* __restrict__ ns1, const float* __restrict__ ns2,
                            const float* __restrict__ eg_, const float* __restrict__ eb_,
                            const float* __restrict__ ng_, const float* __restrict__ nb_,
                            float* __restrict__ params) {
  int d = threadIdx.x;  // 128
  float em = es1[d] * (1.0f / NE);
  float ev = fmaxf(es2[d] * (1.0f / NE) - em * em, 0.0f);
  float esc = eg_[d] * rsqrtf(ev + 1e-5f);
  params[d] = esc;
  params[128 + d] = eb_[d] - em * esc;
  float nm = ns1[d] * (1.0f / NN);
  float nv = fmaxf(ns2[d] * (1.0f / NN) - nm * nm, 0.0f);
  float nsc = ng_[d] * rsqrtf(nv + 1e-5f);
  params[256 + d] = nsc;
  params[384 + d] = nb_[d] - nm * nsc;
}

// ---------- kernel 4: x_out = x + softplus(BN(us + (deg>0)*ud)) ----------
__global__ __launch_bounds__(256) void node_fin2_k(
    const float* __restrict__ x, const u16* __restrict__ us,
    const u16* __restrict__ ud, const u32* __restrict__ cnt,
    const float* __restrict__ params, float* __restrict__ out) {
  size_t t = (size_t)blockIdx.x * 256 + threadIdx.x;
  size_t base = t * 8;
  int d0 = (int)(base & 127);
  int n = (int)(t >> 4);
  float g = (cnt[n] != 0u) ? 1.0f : 0.0f;
  float4 xa = *(const float4*)(x + base);
  float4 xb = *(const float4*)(x + base + 4);
  float xv[8] = {xa.x, xa.y, xa.z, xa.w, xb.x, xb.y, xb.z, xb.w};
  uint4 usv = *(const uint4*)(us + base);
  uint4 udv = *(const uint4*)(ud + base);
  const u16* up = (const u16*)&usv;
  const u16* dp = (const u16*)&udv;
  float o[8];
#pragma unroll
  for (int j = 0; j < 8; ++j) {
    float z = bf2f(up[j]) + g * bf2f(dp[j]);
    float bnv = z * params[256 + d0 + j] + params[384 + d0 + j];
    o[j] = xv[j] + splus(bnv);
  }
  *(float4*)(out + base) = make_float4(o[0], o[1], o[2], o[3]);
  *(float4*)(out + base + 4) = make_float4(o[4], o[5], o[6], o[7]);
}

// ---------- kernel 5: y_out = edge_attr + softplus(BN(mge)) — pure streaming ----------
__global__ __launch_bounds__(256) void edge_fin_k(
    const float* __restrict__ edge_attr, const u16* __restrict__ mge,
    const float* __restrict__ params, float* __restrict__ out) {
  size_t t = (size_t)blockIdx.x * 256 + threadIdx.x;
  size_t base = t * 8;
  int d0 = (int)(base & 127);
  float4 ea = *(const float4*)(edge_attr + base);
  float4 eb = *(const float4*)(edge_attr + base + 4);
  float ev[8] = {ea.x, ea.y, ea.z, ea.w, eb.x, eb.y, eb.z, eb.w};
  uint4 mv_ = *(const uint4*)(mge + base);
  const u16* mp = (const u16*)&mv_;
  float o[8];
#pragma unroll
  for (int j = 0; j < 8; ++j) {
    float m = bf2f(mp[j]);
    float bnv = m * params[d0 + j] + params[128 + d0 + j];
    o[j] = ev[j] + splus(bnv);
  }
  *(float4*)(out + base) = make_float4(o[0], o[1], o[2], o[3]);
  *(float4*)(out + base + 4) = make_float4(o[4], o[5], o[6], o[7]);
}

// ---------- launch ----------
extern "C" void kernel_launch(void* const* d_in, const int* in_sizes, int n_in,
                              void* d_out, int out_size, void* d_ws, size_t ws_size,
                              hipStream_t stream) {
  const float* x        = (const float*)d_in[0];
  const void*  eidx     = d_in[1];
  const float* edge_att = (const float*)d_in[2];
  const float* Wsg = (const float*)d_in[3];  const float* bsg = (const float*)d_in[4];
  const float* Wdg = (const float*)d_in[5];  const float* bdg = (const float*)d_in[6];
  const float* Weg = (const float*)d_in[7];  const float* beg = (const float*)d_in[8];
  const float* Wsu = (const float*)d_in[9];  const float* bsu = (const float*)d_in[10];
  const float* Wdu = (const float*)d_in[11]; const float* bdu = (const float*)d_in[12];
  const float* bng = (const float*)d_in[13]; const float* bnb = (const float*)d_in[14];
  const float* beg_g = (const float*)d_in[15]; const float* beb = (const float*)d_in[16];

  char* ws = (char*)d_ws;
  u16*   g_src  = (u16*)(ws + 0);              // NN*128 bf16
  u16*   g_dst  = (u16*)(ws + 10240000);
  u16*   u_dst  = (u16*)(ws + 20480000);
  u16*   u_src  = (u16*)(ws + 30720000);
  float* stats  = (float*)(ws + 40960000);     // es1,es2,ns1,ns2,params (1024 f32)
  u32*   flags  = (u32*)(ws + 40964096);
  u16*   wbuf   = (u16*)(ws + 40968192);       // 5*16384 bf16
  u32*   cnt    = (u32*)(ws + 41132032);       // 40000 u32 (in-degree)
  u16*   mge    = (u16*)(ws + 41292032);       // NE*128 bf16 (full gate pre-activation)

  hipMemsetAsync(stats, 0, 4096, stream);
  hipMemsetAsync(cnt, 0, 160000, stream);

  sniff_k<<<1, 64, 0, stream>>>((const u32*)bng, (const u32*)eidx, flags);
  wconv5_k<<<dim3(64, 5), 256, 0, stream>>>(Wsg, Wdg, Wdu, Wsu, Weg, wbuf);
  hist_k<<<NE / 256, 256, 0, stream>>>(eidx, cnt, flags);
  node_gemm_k<<<NN / 64, 256, 0, stream>>>(x, wbuf, bsg, bdg, bdu, bsu, cnt,
                                           g_src, g_dst, u_dst, u_src, stats);
  edge_gemm_k<<<NE / (64 * TPW), 256, 0, stream>>>(edge_att, wbuf + 4 * 16384, beg,
                                                   g_src, g_dst, eidx,
                                                   mge, stats, flags);
  stats_fin_k<<<1, 128, 0, stream>>>(stats, stats + 128, stats + 256, stats + 384,
                                     beg_g, beb, bng, bnb, stats + 512);
  node_fin2_k<<<(NN * 128) / 2048, 256, 0, stream>>>(x, u_src, u_dst, cnt,
                                                     stats + 512, (float*)d_out);
  edge_fin_k<<<(NE * 128) / 2048, 256, 0, stream>>>(edge_att, mge, stats + 512,
                                                    (float*)d_out + (size_t)NN * 128);
}